// Round 4
// baseline (401.778 us; speedup 1.0000x reference)
//
#include <hip/hip_runtime.h>

#define M_NODES 16384
#define NNBR 32
#define RREL 237
#define ATTN_SCALE 0.25f   // (128/8)^-0.5
#define LN_EPS 1e-5f

typedef float float4v __attribute__((ext_vector_type(4)));

// ---------------------------------------------------------------------------
// Fully fused, zero-workspace kernel, ALL-FP32 I/O (reference dtypes).
// One block (256 thr) per node. Algebra removes per-neighbor K/V projections:
//   logit[h][n] = SCALE * ( sum_j nbk[n][j]*qk[h][j] + qb[h] )
//     where qk[h][j] = sum_{dh} Wk[j][h*16+dh] * q[h*16+dh]   (heads partition D)
//   out_attn     = (P @ nbv) @ Wv + bv      (mix neighbors BEFORE projecting)
// Per-node arithmetic ~130K MACs instead of ~1.07M.
// ---------------------------------------------------------------------------
__global__ __launch_bounds__(256) void rga_fused(
    const float* __restrict__ entity,
    const int* __restrict__ nidx,
    const int* __restrict__ nrel,
    const int* __restrict__ nmask,
    const float* __restrict__ Wq, const float* __restrict__ bq,
    const float* __restrict__ Wk, const float* __restrict__ bk,
    const float* __restrict__ Wv, const float* __restrict__ bv,
    const float* __restrict__ Wo, const float* __restrict__ bo,
    const float* __restrict__ rel_table,
    const float* __restrict__ gamma_, const float* __restrict__ beta_,
    float* __restrict__ outp) {
    __shared__ float er[128];          // entity row
    __shared__ float qv[128];          // q row
    __shared__ float nbk[32][132];     // gathered nbr + rel rows (K input)
    __shared__ float nbv[32][132];     // gathered nbr rows (V input)
    __shared__ float qk[8][132];       // head-folded q @ Wk^T
    __shared__ float qb[8];            // q . bk per head
    __shared__ float Lg[8][33];        // logits -> P (in place)
    __shared__ float pv[8][132];       // P @ nbv
    __shared__ float oat[128];         // attention output row
    __shared__ float ypart[2][128];    // half-split partial sums (reused)
    __shared__ float red[4];
    __shared__ int midx[32], mrel[32], mmask[32];

    int m = blockIdx.x;
    int t = threadIdx.x;

    // P0: indices/mask (clamped -> wild gathers impossible) + entity row
    if (t < 32) {
        int mk = nmask[m * NNBR + t];
        int ix = nidx[m * NNBR + t];
        int ir = nrel[m * NNBR + t];
        if (!mk) { ix = 0; ir = 0; }
        ix = ix < 0 ? 0 : (ix > M_NODES - 1 ? M_NODES - 1 : ix);
        ir = ir < 0 ? 0 : (ir > RREL - 1 ? RREL - 1 : ir);
        mmask[t] = mk; midx[t] = ix; mrel[t] = ir;
    }
    if (t >= 128) er[t - 128] = entity[m * 128 + (t - 128)];
    __syncthreads();

    // P1: q = er @ Wq + bq   (j-range split across thread halves)
    {
        int half = t >> 7, d = t & 127, j0 = half * 64;
        float acc = 0.f;
        #pragma unroll 8
        for (int j = 0; j < 64; ++j) acc += er[j0 + j] * Wq[(j0 + j) * 128 + d];
        ypart[half][d] = acc;
    }
    __syncthreads();
    if (t < 128) qv[t] = ypart[0][t] + ypart[1][t] + bq[t];
    __syncthreads();

    // P2a: qk[h][j] = sum_dh Wk[j][h*16+dh] * qv[h*16+dh]
    #pragma unroll
    for (int rep = 0; rep < 4; ++rep) {
        int o = rep * 256 + t;
        int h = o >> 7, j = o & 127;
        const float* wr = &Wk[j * 128 + h * 16];
        float4v w0 = *(const float4v*)&wr[0];
        float4v w1 = *(const float4v*)&wr[4];
        float4v w2 = *(const float4v*)&wr[8];
        float4v w3 = *(const float4v*)&wr[12];
        float s = 0.f;
        #pragma unroll
        for (int e = 0; e < 4; ++e) s += w0[e] * qv[h * 16 + e];
        #pragma unroll
        for (int e = 0; e < 4; ++e) s += w1[e] * qv[h * 16 + 4 + e];
        #pragma unroll
        for (int e = 0; e < 4; ++e) s += w2[e] * qv[h * 16 + 8 + e];
        #pragma unroll
        for (int e = 0; e < 4; ++e) s += w3[e] * qv[h * 16 + 12 + e];
        qk[h][j] = s;
    }
    // P2b: qb[h] = q . bk restricted to head h
    if (t < 8) {
        float s = 0.f;
        #pragma unroll
        for (int dh = 0; dh < 16; ++dh) s += qv[t * 16 + dh] * bk[t * 16 + dh];
        qb[t] = s;
    }
    // P2c: gather neighbor rows (+rel) into LDS. 1024 float4 chunks per table.
    #pragma unroll
    for (int rep = 0; rep < 4; ++rep) {
        int id = rep * 256 + t;          // 0..1023: n = id>>5, chunk = id&31
        int n = id >> 5, c = (id & 31) * 4;
        int ix = midx[n], ir = mrel[n];
        float4v e4 = *(const float4v*)&entity[ix * 128 + c];
        float4v r4 = *(const float4v*)&rel_table[ir * 128 + c];
        #pragma unroll
        for (int j2 = 0; j2 < 4; ++j2) {
            nbk[n][c + j2] = e4[j2] + r4[j2];
            nbv[n][c + j2] = e4[j2];
        }
    }
    __syncthreads();

    // P3: logits. 256 thr = 32 nbrs x 8 heads
    {
        int n = t >> 3, h = t & 7;
        float acc = qb[h];
        #pragma unroll 8
        for (int j = 0; j < 128; ++j) acc += nbk[n][j] * qk[h][j];
        float lf = acc * ATTN_SCALE;
        if (!mmask[n]) lf = -1e30f;
        Lg[h][n] = lf;
    }
    __syncthreads();

    // P4: masked softmax, in place. 256 thr = 8 heads x 32 nbrs
    {
        int h = t >> 5, n = t & 31;
        float lf = Lg[h][n];
        float mx = lf;
        #pragma unroll
        for (int off = 16; off >= 1; off >>= 1) mx = fmaxf(mx, __shfl_xor(mx, off, 32));
        float p = __expf(lf - mx);
        float s = p;
        #pragma unroll
        for (int off = 16; off >= 1; off >>= 1) s += __shfl_xor(s, off, 32);
        Lg[h][n] = p / s;
    }
    __syncthreads();

    // P5: pv[h][j] = sum_n P[h][n] * nbv[n][j]
    #pragma unroll
    for (int rep = 0; rep < 4; ++rep) {
        int o = rep * 256 + t;
        int h = o >> 7, j = o & 127;
        float acc = 0.f;
        #pragma unroll 8
        for (int n = 0; n < 32; ++n) acc += Lg[h][n] * nbv[n][j];
        pv[h][j] = acc;
    }
    __syncthreads();

    // P6: out_attn[d] = sum_j pv[d>>4][j] * Wv[j][d] + bv[d]  (half-split j)
    {
        int half = t >> 7, d = t & 127, j0 = half * 64;
        int h = d >> 4;
        float acc = 0.f;
        #pragma unroll 8
        for (int j = 0; j < 64; ++j) acc += pv[h][j0 + j] * Wv[(j0 + j) * 128 + d];
        ypart[half][d] = acc;
    }
    __syncthreads();
    if (t < 128) oat[t] = ypart[0][t] + ypart[1][t] + bv[t];
    __syncthreads();

    // P7: y[d] = sum_j oat[j] * Wo[j][d]   (half-split j; ypart reused)
    {
        int half = t >> 7, d = t & 127, j0 = half * 64;
        float acc = 0.f;
        #pragma unroll 8
        for (int j = 0; j < 64; ++j) acc += oat[j0 + j] * Wo[(j0 + j) * 128 + d];
        ypart[half][d] = acc;
    }
    __syncthreads();

    // P8: residual + LayerNorm over 128 dims
    float x = 0.f;
    if (t < 128) {
        x = er[t] + ypart[0][t] + ypart[1][t] + bo[t];
        float s1 = x, s2 = x * x;
        #pragma unroll
        for (int off = 32; off >= 1; off >>= 1) {
            s1 += __shfl_xor(s1, off, 64);
            s2 += __shfl_xor(s2, off, 64);
        }
        if ((t & 63) == 0) { red[(t >> 6) * 2] = s1; red[(t >> 6) * 2 + 1] = s2; }
    }
    __syncthreads();
    if (t < 128) {
        float mu  = (red[0] + red[2]) * (1.0f / 128.0f);
        float ms  = (red[1] + red[3]) * (1.0f / 128.0f);
        float var = fmaxf(ms - mu * mu, 0.0f);
        float rs  = rsqrtf(var + LN_EPS);
        outp[m * 128 + t] = (x - mu) * rs * gamma_[t] + beta_[t];
    }
}

// ---------------------------------------------------------------------------
extern "C" void kernel_launch(void* const* d_in, const int* in_sizes, int n_in,
                              void* d_out, int out_size, void* d_ws, size_t ws_size,
                              hipStream_t stream) {
    const float* entity    = (const float*)d_in[0];
    const int*   nidx      = (const int*)d_in[1];
    const int*   nrel      = (const int*)d_in[2];
    const int*   nmask     = (const int*)d_in[3];
    const float* Wq        = (const float*)d_in[4];
    const float* bq        = (const float*)d_in[5];
    const float* Wk        = (const float*)d_in[6];
    const float* bk        = (const float*)d_in[7];
    const float* Wv        = (const float*)d_in[8];
    const float* bv        = (const float*)d_in[9];
    const float* Wo        = (const float*)d_in[10];
    const float* bo        = (const float*)d_in[11];
    const float* rel_table = (const float*)d_in[12];
    const float* gamma_    = (const float*)d_in[13];
    const float* beta_     = (const float*)d_in[14];

    (void)d_ws; (void)ws_size;   // zero workspace usage

    rga_fused<<<dim3(M_NODES), 256, 0, stream>>>(
        entity, nidx, nrel, nmask, Wq, bq, Wk, bk, Wv, bv, Wo, bo,
        rel_table, gamma_, beta_, (float*)d_out);
}

// Round 5
// 357.837 us; speedup vs baseline: 1.1228x; 1.1228x over previous
//
#include <hip/hip_runtime.h>

#define M_NODES 16384
#define NNBR 32
#define RREL 237
#define ATTN_SCALE 0.25f   // (128/8)^-0.5
#define LN_EPS 1e-5f

typedef float float4v __attribute__((ext_vector_type(4)));
typedef unsigned int uint4v __attribute__((ext_vector_type(4)));

__device__ __forceinline__ unsigned short f2bfu(float f) {
    unsigned int x = __builtin_bit_cast(unsigned int, f);
    unsigned int lsb = (x >> 16) & 1u;
    x += 0x7fffu + lsb;                 // round-to-nearest-even
    return (unsigned short)(x >> 16);
}
__device__ __forceinline__ unsigned int pack2(float a, float b) {
    return (unsigned int)f2bfu(a) | ((unsigned int)f2bfu(b) << 16);
}
__device__ __forceinline__ float unpk_lo(unsigned int u) {
    return __builtin_bit_cast(float, u << 16);
}
__device__ __forceinline__ float unpk_hi(unsigned int u) {
    return __builtin_bit_cast(float, u & 0xffff0000u);
}

// ---------------------------------------------------------------------------
// Fused, zero-workspace, fp32 kernel — round 5: occupancy + LDS-instruction
// restructure. One block (256 thr) per node.
//   - logits fused into the gather (nbk array eliminated; 8-lane shfl reduce)
//   - nbv stored as packed bf16 pairs (8.7 KB)
//   - all bulk LDS reads vectorized to b128
// LDS ~21.2 KB -> 6 blocks/CU (was 46.6 KB -> 3).
// ---------------------------------------------------------------------------
__global__ __launch_bounds__(256, 6) void rga_fused(
    const float* __restrict__ entity,
    const int* __restrict__ nidx,
    const int* __restrict__ nrel,
    const int* __restrict__ nmask,
    const float* __restrict__ Wq, const float* __restrict__ bq,
    const float* __restrict__ Wk, const float* __restrict__ bk,
    const float* __restrict__ Wv, const float* __restrict__ bv,
    const float* __restrict__ Wo, const float* __restrict__ bo,
    const float* __restrict__ rel_table,
    const float* __restrict__ gamma_, const float* __restrict__ beta_,
    float* __restrict__ outp) {
    __shared__ __align__(16) float er[128];        // entity row
    __shared__ __align__(16) float qv[128];        // q row
    __shared__ float qb[8];                        // q . bk per head
    __shared__ __align__(16) float qk[8 * 132];    // head-folded q@Wk^T (row stride 132)
    __shared__ __align__(16) unsigned int nbvp[32 * 68]; // nbr rows, bf16-packed (row stride 68 uints)
    __shared__ float Lg[8][33];                    // logits -> P in place
    __shared__ __align__(16) float pv[8 * 132];    // P @ nbv (row stride 132)
    __shared__ __align__(16) float oat[128];       // attention output row
    __shared__ float ypart[2][128];
    __shared__ float red[4];
    __shared__ int midx[32], mrel[32], mmask[32];

    int m = blockIdx.x;
    int t = threadIdx.x;

    // P0: indices/mask (clamped) + entity row
    if (t < 32) {
        int mk = nmask[m * NNBR + t];
        int ix = nidx[m * NNBR + t];
        int ir = nrel[m * NNBR + t];
        if (!mk) { ix = 0; ir = 0; }
        ix = ix < 0 ? 0 : (ix > M_NODES - 1 ? M_NODES - 1 : ix);
        ir = ir < 0 ? 0 : (ir > RREL - 1 ? RREL - 1 : ir);
        mmask[t] = mk; midx[t] = ix; mrel[t] = ir;
    }
    if (t >= 128) er[t - 128] = entity[m * 128 + (t - 128)];
    __syncthreads();

    // P1: q = er @ Wq + bq (half-split j; er via b128 broadcast reads)
    {
        int half = t >> 7, d = t & 127, j0 = half * 64;
        const float4v* e4 = (const float4v*)&er[j0];
        float acc = 0.f;
        #pragma unroll 4
        for (int c = 0; c < 16; ++c) {
            float4v ev = e4[c];
            #pragma unroll
            for (int k = 0; k < 4; ++k)
                acc += ev[k] * Wq[(j0 + c * 4 + k) * 128 + d];
        }
        ypart[half][d] = acc;
    }
    __syncthreads();
    if (t < 128) qv[t] = ypart[0][t] + ypart[1][t] + bq[t];
    __syncthreads();

    // P2a: qk[h][j] = sum_dh Wk[j][h*16+dh] * qv[h*16+dh]
    #pragma unroll
    for (int rep = 0; rep < 4; ++rep) {
        int o = rep * 256 + t;
        int h = o >> 7, j = o & 127;
        const float4v* wr = (const float4v*)&Wk[j * 128 + h * 16];
        const float4v* q4 = (const float4v*)&qv[h * 16];
        float s = 0.f;
        #pragma unroll
        for (int c = 0; c < 4; ++c) {
            float4v w = wr[c], q = q4[c];
            #pragma unroll
            for (int k = 0; k < 4; ++k) s += w[k] * q[k];
        }
        qk[h * 132 + j] = s;
    }
    // P2b: qb[h]
    if (t < 8) {
        float s = 0.f;
        #pragma unroll
        for (int dh = 0; dh < 16; ++dh) s += qv[t * 16 + dh] * bk[t * 16 + dh];
        qb[t] = s;
    }
    __syncthreads();

    // P2c: fused gather + logits. t -> (n = t>>3, c16 = t&7, j0 = c16*16)
    {
        int n = t >> 3, c16 = t & 7, j0 = c16 * 16;
        int ix = midx[n], ir = mrel[n];
        const float4v* ep = (const float4v*)&entity[ix * 128 + j0];
        const float4v* rp = (const float4v*)&rel_table[ir * 128 + j0];
        float ev[16], kv[16];
        #pragma unroll
        for (int c = 0; c < 4; ++c) {
            float4v e4 = ep[c], r4 = rp[c];
            #pragma unroll
            for (int k = 0; k < 4; ++k) {
                ev[c * 4 + k] = e4[k];
                kv[c * 4 + k] = e4[k] + r4[k];
            }
        }
        // store nbv (bf16-packed, 8 uints = 2 x uint4)
        uint4v u0, u1;
        #pragma unroll
        for (int k = 0; k < 4; ++k) u0[k] = pack2(ev[2 * k], ev[2 * k + 1]);
        #pragma unroll
        for (int k = 0; k < 4; ++k) u1[k] = pack2(ev[8 + 2 * k], ev[9 + 2 * k]);
        *(uint4v*)&nbvp[n * 68 + c16 * 8]     = u0;
        *(uint4v*)&nbvp[n * 68 + c16 * 8 + 4] = u1;
        // 8 head-partial logits over this thread's 16 j's
        float acc[8];
        #pragma unroll
        for (int h = 0; h < 8; ++h) {
            const float4v* qrow = (const float4v*)&qk[h * 132 + j0];
            float s = 0.f;
            #pragma unroll
            for (int c = 0; c < 4; ++c) {
                float4v q = qrow[c];
                #pragma unroll
                for (int k = 0; k < 4; ++k) s += q[k] * kv[c * 4 + k];
            }
            acc[h] = s;
        }
        // reduce across the 8 j-chunk lanes (contiguous within wave)
        #pragma unroll
        for (int off = 1; off < 8; off <<= 1) {
            #pragma unroll
            for (int h = 0; h < 8; ++h) acc[h] += __shfl_xor(acc[h], off, 8);
        }
        if (c16 == 0) {
            #pragma unroll
            for (int h = 0; h < 8; ++h) {
                float lf = (acc[h] + qb[h]) * ATTN_SCALE;
                if (!mmask[n]) lf = -1e30f;
                Lg[h][n] = lf;
            }
        }
    }
    __syncthreads();

    // P4: masked softmax in place. 256 thr = 8 heads x 32 nbrs
    {
        int h = t >> 5, n = t & 31;
        float lf = Lg[h][n];
        float mx = lf;
        #pragma unroll
        for (int off = 16; off >= 1; off >>= 1) mx = fmaxf(mx, __shfl_xor(mx, off, 32));
        float p = __expf(lf - mx);
        float s = p;
        #pragma unroll
        for (int off = 16; off >= 1; off >>= 1) s += __shfl_xor(s, off, 32);
        Lg[h][n] = p / s;
    }
    __syncthreads();

    // P5: pv[h][j..j+3] = sum_n P[h][n] * nbv[n][j..j+3]. t -> (h = t>>5, c4 = t&31)
    {
        int h = t >> 5, c4 = t & 31;
        float4v a = (float4v){0.f, 0.f, 0.f, 0.f};
        #pragma unroll 8
        for (int n = 0; n < 32; ++n) {
            float p = Lg[h][n];
            unsigned int w0 = nbvp[n * 68 + c4 * 2];
            unsigned int w1 = nbvp[n * 68 + c4 * 2 + 1];
            a[0] += p * unpk_lo(w0);
            a[1] += p * unpk_hi(w0);
            a[2] += p * unpk_lo(w1);
            a[3] += p * unpk_hi(w1);
        }
        *(float4v*)&pv[h * 132 + c4 * 4] = a;
    }
    __syncthreads();

    // P6: out_attn[d] = sum_j pv[d>>4][j] * Wv[j][d] + bv[d] (half-split j)
    {
        int half = t >> 7, d = t & 127, j0 = half * 64;
        int h = d >> 4;
        const float4v* p4 = (const float4v*)&pv[h * 132 + j0];
        float acc = 0.f;
        #pragma unroll 4
        for (int c = 0; c < 16; ++c) {
            float4v p = p4[c];
            #pragma unroll
            for (int k = 0; k < 4; ++k)
                acc += p[k] * Wv[(j0 + c * 4 + k) * 128 + d];
        }
        ypart[half][d] = acc;
    }
    __syncthreads();
    if (t < 128) oat[t] = ypart[0][t] + ypart[1][t] + bv[t];
    __syncthreads();

    // P7: y[d] = sum_j oat[j] * Wo[j][d] (half-split j)
    {
        int half = t >> 7, d = t & 127, j0 = half * 64;
        const float4v* o4 = (const float4v*)&oat[j0];
        float acc = 0.f;
        #pragma unroll 4
        for (int c = 0; c < 16; ++c) {
            float4v o = o4[c];
            #pragma unroll
            for (int k = 0; k < 4; ++k)
                acc += o[k] * Wo[(j0 + c * 4 + k) * 128 + d];
        }
        ypart[half][d] = acc;
    }
    __syncthreads();

    // P8: residual + LayerNorm
    float x = 0.f;
    if (t < 128) {
        x = er[t] + ypart[0][t] + ypart[1][t] + bo[t];
        float s1 = x, s2 = x * x;
        #pragma unroll
        for (int off = 32; off >= 1; off >>= 1) {
            s1 += __shfl_xor(s1, off, 64);
            s2 += __shfl_xor(s2, off, 64);
        }
        if ((t & 63) == 0) { red[(t >> 6) * 2] = s1; red[(t >> 6) * 2 + 1] = s2; }
    }
    __syncthreads();
    if (t < 128) {
        float mu  = (red[0] + red[2]) * (1.0f / 128.0f);
        float ms  = (red[1] + red[3]) * (1.0f / 128.0f);
        float var = fmaxf(ms - mu * mu, 0.0f);
        float rs  = rsqrtf(var + LN_EPS);
        outp[m * 128 + t] = (x - mu) * rs * gamma_[t] + beta_[t];
    }
}

// ---------------------------------------------------------------------------
extern "C" void kernel_launch(void* const* d_in, const int* in_sizes, int n_in,
                              void* d_out, int out_size, void* d_ws, size_t ws_size,
                              hipStream_t stream) {
    const float* entity    = (const float*)d_in[0];
    const int*   nidx      = (const int*)d_in[1];
    const int*   nrel      = (const int*)d_in[2];
    const int*   nmask     = (const int*)d_in[3];
    const float* Wq        = (const float*)d_in[4];
    const float* bq        = (const float*)d_in[5];
    const float* Wk        = (const float*)d_in[6];
    const float* bk        = (const float*)d_in[7];
    const float* Wv        = (const float*)d_in[8];
    const float* bv        = (const float*)d_in[9];
    const float* Wo        = (const float*)d_in[10];
    const float* bo        = (const float*)d_in[11];
    const float* rel_table = (const float*)d_in[12];
    const float* gamma_    = (const float*)d_in[13];
    const float* beta_     = (const float*)d_in[14];

    (void)d_ws; (void)ws_size;   // zero workspace usage

    rga_fused<<<dim3(M_NODES), 256, 0, stream>>>(
        entity, nidx, nrel, nmask, Wq, bq, Wk, bk, Wv, bv, Wo, bo,
        rel_table, gamma_, beta_, (float*)d_out);
}

// Round 6
// 217.484 us; speedup vs baseline: 1.8474x; 1.6453x over previous
//
#include <hip/hip_runtime.h>

#define M_NODES 16384
#define NNBR 32
#define RREL 237
#define ATTN_SCALE 0.25f   // (128/8)^-0.5
#define LN_EPS 1e-5f

typedef float float4v __attribute__((ext_vector_type(4)));
typedef float float2v __attribute__((ext_vector_type(2)));
typedef unsigned int uint4v __attribute__((ext_vector_type(4)));

// ===========================================================================
// FAST PATH (requires ~33.7 MB workspace)
// ===========================================================================

// ---------------------------------------------------------------------------
// Register-tiled fp32 GEMM block: OUT[rbase..rbase+127][0..127] =
//   A[rows][128] @ W[128][128] (+bias). 256 thr = 16x16, each 8x8 micro-tile.
// K staged in 32-chunks: At (transposed, pad 132) + Bc (natural).
// ---------------------------------------------------------------------------
__device__ __forceinline__ void gemm_core(
    const float* __restrict__ A, const float* __restrict__ W,
    int arows, int rbase, float* At, float* Bc, float acc[8][8]) {
    int t = threadIdx.x;
    int tr = t >> 4, tc = t & 15;
    float4v* At4 = (float4v*)At;
    float4v* Bc4 = (float4v*)Bc;

    #pragma unroll
    for (int i = 0; i < 8; ++i)
        #pragma unroll
        for (int j = 0; j < 8; ++j) acc[i][j] = 0.f;

    for (int kc = 0; kc < 4; ++kc) {
        int k0 = kc * 32;
        // stage A chunk transposed: At[k][r] = A[rbase+r][k0+k]
        #pragma unroll
        for (int i = 0; i < 4; ++i) {
            int s = t + i * 256;           // 1024 float4 slots
            int r = s >> 3, q = s & 7;     // row, float4-within-row
            int rr = rbase + r; if (rr >= arows) rr = arows - 1;
            float4v v = *(const float4v*)&A[rr * 128 + k0 + q * 4];
            At[(q * 4 + 0) * 132 + r] = v[0];
            At[(q * 4 + 1) * 132 + r] = v[1];
            At[(q * 4 + 2) * 132 + r] = v[2];
            At[(q * 4 + 3) * 132 + r] = v[3];
        }
        // stage W chunk natural: Bc[k][c] = W[k0+k][c]
        #pragma unroll
        for (int i = 0; i < 4; ++i) {
            int s = t + i * 256;           // 1024 float4 slots
            int k = s >> 5, q = s & 31;
            Bc4[k * 32 + q] = *(const float4v*)&W[(k0 + k) * 128 + q * 4];
        }
        __syncthreads();
        #pragma unroll
        for (int k = 0; k < 32; ++k) {
            float4v a0 = At4[k * 33 + tr * 2];
            float4v a1 = At4[k * 33 + tr * 2 + 1];
            float4v b0 = Bc4[k * 32 + tc * 2];
            float4v b1 = Bc4[k * 32 + tc * 2 + 1];
            float av[8] = {a0[0], a0[1], a0[2], a0[3], a1[0], a1[1], a1[2], a1[3]};
            float bv[8] = {b0[0], b0[1], b0[2], b0[3], b1[0], b1[1], b1[2], b1[3]};
            #pragma unroll
            for (int i = 0; i < 8; ++i)
                #pragma unroll
                for (int j = 0; j < 8; ++j) acc[i][j] += av[i] * bv[j];
        }
        __syncthreads();
    }
}

// K1: four projections in one launch. grid (128, 4)
//   y=0: EQ = entity@Wq+bq   y=1: EK = entity@Wk
//   y=2: EV = entity@Wv+bv   y=3: RK = rel_table@Wk+bk (237 rows, x<2)
__global__ __launch_bounds__(256) void gemm4(
    const float* __restrict__ entity, const float* __restrict__ rel_table,
    const float* __restrict__ Wq, const float* __restrict__ bq,
    const float* __restrict__ Wk, const float* __restrict__ bk,
    const float* __restrict__ Wv, const float* __restrict__ bv,
    float* __restrict__ EQ, float* __restrict__ EK,
    float* __restrict__ EV, float* __restrict__ RK) {
    __shared__ __align__(16) float At[32 * 132];
    __shared__ __align__(16) float Bc[32 * 128];

    int y = blockIdx.y;
    const float* A; const float* W; const float* bias; float* OUT; int arows;
    if (y == 0)      { A = entity;    W = Wq; bias = bq;      OUT = EQ; arows = M_NODES; }
    else if (y == 1) { A = entity;    W = Wk; bias = nullptr; OUT = EK; arows = M_NODES; }
    else if (y == 2) { A = entity;    W = Wv; bias = bv;      OUT = EV; arows = M_NODES; }
    else             { A = rel_table; W = Wk; bias = bk;      OUT = RK; arows = RREL;    }
    int rbase = blockIdx.x * 128;
    if (rbase >= arows) return;

    float acc[8][8];
    gemm_core(A, W, arows, rbase, At, Bc, acc);

    int t = threadIdx.x, tr = t >> 4, tc = t & 15;
    float bb[8] = {0, 0, 0, 0, 0, 0, 0, 0};
    if (bias) {
        float4v g0 = *(const float4v*)&bias[tc * 8];
        float4v g1 = *(const float4v*)&bias[tc * 8 + 4];
        #pragma unroll
        for (int j = 0; j < 4; ++j) { bb[j] = g0[j]; bb[4 + j] = g1[j]; }
    }
    #pragma unroll
    for (int i = 0; i < 8; ++i) {
        int r = rbase + tr * 8 + i;
        if (r < arows) {
            float4v o0, o1;
            #pragma unroll
            for (int j = 0; j < 4; ++j) { o0[j] = acc[i][j] + bb[j]; o1[j] = acc[i][4 + j] + bb[4 + j]; }
            *(float4v*)&OUT[r * 128 + tc * 8]     = o0;
            *(float4v*)&OUT[r * 128 + tc * 8 + 4] = o1;
        }
    }
}

// K2: wave-per-node attention. grid 4096 x 256 thr (4 nodes/block).
// lane = half*32+n: computes 4 full head-dots (head dims within its 64-dim half).
__global__ __launch_bounds__(256) void attn_gather(
    const int* __restrict__ nidx, const int* __restrict__ nrel,
    const int* __restrict__ nmask,
    const float* __restrict__ EQ, const float* __restrict__ EK,
    const float* __restrict__ EV, const float* __restrict__ RK,
    float* __restrict__ OAT) {
    __shared__ float Pl[4][8][32];
    __shared__ int mix[4][32];

    int w = threadIdx.x >> 6, l = threadIdx.x & 63;
    int m = blockIdx.x * 4 + w;
    int half = l >> 5, n = l & 31;

    int mk = nmask[m * NNBR + n];
    int ix = nidx[m * NNBR + n];
    int ir = nrel[m * NNBR + n];
    if (!mk) { ix = 0; ir = 0; }
    ix = ix < 0 ? 0 : (ix > M_NODES - 1 ? M_NODES - 1 : ix);
    ir = ir < 0 ? 0 : (ir > RREL - 1 ? RREL - 1 : ir);
    if (l < 32) mix[w][l] = ix;            // lanes 0..31 carry n=l

    // logits for heads half*4 .. half*4+3 (dims half*64 .. half*64+63)
    const float4v* eq4 = (const float4v*)&EQ[m * 128 + half * 64];
    const float4v* ek4 = (const float4v*)&EK[ix * 128 + half * 64];
    const float4v* rk4 = (const float4v*)&RK[ir * 128 + half * 64];
    float acc[4] = {0.f, 0.f, 0.f, 0.f};
    #pragma unroll
    for (int c = 0; c < 16; ++c) {
        float4v q = eq4[c], e = ek4[c], r = rk4[c];
        int hh = c >> 2;
        #pragma unroll
        for (int j = 0; j < 4; ++j) acc[hh] += q[j] * (e[j] + r[j]);
    }
    #pragma unroll
    for (int hh = 0; hh < 4; ++hh) {
        float lf = acc[hh] * ATTN_SCALE;
        if (!mk) lf = -1e30f;
        float mx = lf;
        #pragma unroll
        for (int off = 16; off >= 1; off >>= 1) mx = fmaxf(mx, __shfl_xor(mx, off, 32));
        float p = __expf(lf - mx);
        float s = p;
        #pragma unroll
        for (int off = 16; off >= 1; off >>= 1) s += __shfl_xor(s, off, 32);
        Pl[w][half * 4 + hh][n] = p / s;
    }
    // PV: lane -> dims d0=2l, d0+1 (head h0 = l>>3); wave-private LDS, no barrier
    int d0 = l * 2, h0 = l >> 3;
    float o0 = 0.f, o1 = 0.f;
    #pragma unroll 8
    for (int n2 = 0; n2 < 32; ++n2) {
        float pp = Pl[w][h0][n2];
        int ixx = mix[w][n2];
        float2v v = *(const float2v*)&EV[ixx * 128 + d0];
        o0 += pp * v[0];
        o1 += pp * v[1];
    }
    float2v o; o[0] = o0; o[1] = o1;
    *(float2v*)&OAT[m * 128 + d0] = o;
}

// K3: Y = OAT@Wo + bo + entity, then LayerNorm — fused epilogue. grid 128.
__global__ __launch_bounds__(256) void gemm_wo_ln(
    const float* __restrict__ OAT, const float* __restrict__ Wo,
    const float* __restrict__ bo, const float* __restrict__ entity,
    const float* __restrict__ gamma_, const float* __restrict__ beta_,
    float* __restrict__ OUT) {
    __shared__ __align__(16) float At[32 * 132];
    __shared__ __align__(16) float Bc[32 * 128];

    int rbase = blockIdx.x * 128;
    float acc[8][8];
    gemm_core(OAT, Wo, M_NODES, rbase, At, Bc, acc);

    int t = threadIdx.x, tr = t >> 4, tc = t & 15;
    float bb[8], gg[8], be[8];
    {
        float4v b0 = *(const float4v*)&bo[tc * 8];
        float4v b1 = *(const float4v*)&bo[tc * 8 + 4];
        float4v g0 = *(const float4v*)&gamma_[tc * 8];
        float4v g1 = *(const float4v*)&gamma_[tc * 8 + 4];
        float4v e0 = *(const float4v*)&beta_[tc * 8];
        float4v e1 = *(const float4v*)&beta_[tc * 8 + 4];
        #pragma unroll
        for (int j = 0; j < 4; ++j) {
            bb[j] = b0[j]; bb[4 + j] = b1[j];
            gg[j] = g0[j]; gg[4 + j] = g1[j];
            be[j] = e0[j]; be[4 + j] = e1[j];
        }
    }
    #pragma unroll
    for (int i = 0; i < 8; ++i) {
        int r = rbase + tr * 8 + i;
        float4v e0 = *(const float4v*)&entity[r * 128 + tc * 8];
        float4v e1 = *(const float4v*)&entity[r * 128 + tc * 8 + 4];
        float y[8];
        #pragma unroll
        for (int j = 0; j < 4; ++j) {
            y[j]     = acc[i][j]     + bb[j]     + e0[j];
            y[4 + j] = acc[i][4 + j] + bb[4 + j] + e1[j];
        }
        float s1 = 0.f, s2 = 0.f;
        #pragma unroll
        for (int j = 0; j < 8; ++j) { s1 += y[j]; s2 += y[j] * y[j]; }
        #pragma unroll
        for (int off = 8; off >= 1; off >>= 1) {
            s1 += __shfl_xor(s1, off, 16);
            s2 += __shfl_xor(s2, off, 16);
        }
        float mu  = s1 * (1.0f / 128.0f);
        float var = fmaxf(s2 * (1.0f / 128.0f) - mu * mu, 0.0f);
        float rs  = rsqrtf(var + LN_EPS);
        float4v o0, o1;
        #pragma unroll
        for (int j = 0; j < 4; ++j) {
            o0[j] = (y[j]     - mu) * rs * gg[j]     + be[j];
            o1[j] = (y[4 + j] - mu) * rs * gg[4 + j] + be[4 + j];
        }
        *(float4v*)&OUT[r * 128 + tc * 8]     = o0;
        *(float4v*)&OUT[r * 128 + tc * 8 + 4] = o1;
    }
}

// ===========================================================================
// FALLBACK (round-5 fused kernel, passes at ~314 µs) — used if ws too small
// ===========================================================================
__device__ __forceinline__ unsigned short f2bfu(float f) {
    unsigned int x = __builtin_bit_cast(unsigned int, f);
    unsigned int lsb = (x >> 16) & 1u;
    x += 0x7fffu + lsb;
    return (unsigned short)(x >> 16);
}
__device__ __forceinline__ unsigned int pack2(float a, float b) {
    return (unsigned int)f2bfu(a) | ((unsigned int)f2bfu(b) << 16);
}
__device__ __forceinline__ float unpk_lo(unsigned int u) {
    return __builtin_bit_cast(float, u << 16);
}
__device__ __forceinline__ float unpk_hi(unsigned int u) {
    return __builtin_bit_cast(float, u & 0xffff0000u);
}

__global__ __launch_bounds__(256, 6) void rga_fused(
    const float* __restrict__ entity,
    const int* __restrict__ nidx,
    const int* __restrict__ nrel,
    const int* __restrict__ nmask,
    const float* __restrict__ Wq, const float* __restrict__ bq,
    const float* __restrict__ Wk, const float* __restrict__ bk,
    const float* __restrict__ Wv, const float* __restrict__ bv,
    const float* __restrict__ Wo, const float* __restrict__ bo,
    const float* __restrict__ rel_table,
    const float* __restrict__ gamma_, const float* __restrict__ beta_,
    float* __restrict__ outp) {
    __shared__ __align__(16) float er[128];
    __shared__ __align__(16) float qv[128];
    __shared__ float qb[8];
    __shared__ __align__(16) float qk[8 * 132];
    __shared__ __align__(16) unsigned int nbvp[32 * 68];
    __shared__ float Lg[8][33];
    __shared__ __align__(16) float pv[8 * 132];
    __shared__ __align__(16) float oat[128];
    __shared__ float ypart[2][128];
    __shared__ float red[4];
    __shared__ int midx[32], mrel[32], mmask[32];

    int m = blockIdx.x;
    int t = threadIdx.x;

    if (t < 32) {
        int mk = nmask[m * NNBR + t];
        int ix = nidx[m * NNBR + t];
        int ir = nrel[m * NNBR + t];
        if (!mk) { ix = 0; ir = 0; }
        ix = ix < 0 ? 0 : (ix > M_NODES - 1 ? M_NODES - 1 : ix);
        ir = ir < 0 ? 0 : (ir > RREL - 1 ? RREL - 1 : ir);
        mmask[t] = mk; midx[t] = ix; mrel[t] = ir;
    }
    if (t >= 128) er[t - 128] = entity[m * 128 + (t - 128)];
    __syncthreads();

    {
        int half = t >> 7, d = t & 127, j0 = half * 64;
        const float4v* e4 = (const float4v*)&er[j0];
        float acc = 0.f;
        #pragma unroll 4
        for (int c = 0; c < 16; ++c) {
            float4v ev = e4[c];
            #pragma unroll
            for (int k = 0; k < 4; ++k)
                acc += ev[k] * Wq[(j0 + c * 4 + k) * 128 + d];
        }
        ypart[half][d] = acc;
    }
    __syncthreads();
    if (t < 128) qv[t] = ypart[0][t] + ypart[1][t] + bq[t];
    __syncthreads();

    #pragma unroll
    for (int rep = 0; rep < 4; ++rep) {
        int o = rep * 256 + t;
        int h = o >> 7, j = o & 127;
        const float4v* wr = (const float4v*)&Wk[j * 128 + h * 16];
        const float4v* q4 = (const float4v*)&qv[h * 16];
        float s = 0.f;
        #pragma unroll
        for (int c = 0; c < 4; ++c) {
            float4v w = wr[c], q = q4[c];
            #pragma unroll
            for (int k = 0; k < 4; ++k) s += w[k] * q[k];
        }
        qk[h * 132 + j] = s;
    }
    if (t < 8) {
        float s = 0.f;
        #pragma unroll
        for (int dh = 0; dh < 16; ++dh) s += qv[t * 16 + dh] * bk[t * 16 + dh];
        qb[t] = s;
    }
    __syncthreads();

    {
        int n = t >> 3, c16 = t & 7, j0 = c16 * 16;
        int ix = midx[n], ir = mrel[n];
        const float4v* ep = (const float4v*)&entity[ix * 128 + j0];
        const float4v* rp = (const float4v*)&rel_table[ir * 128 + j0];
        float ev[16], kv[16];
        #pragma unroll
        for (int c = 0; c < 4; ++c) {
            float4v e4 = ep[c], r4 = rp[c];
            #pragma unroll
            for (int k = 0; k < 4; ++k) {
                ev[c * 4 + k] = e4[k];
                kv[c * 4 + k] = e4[k] + r4[k];
            }
        }
        uint4v u0, u1;
        #pragma unroll
        for (int k = 0; k < 4; ++k) u0[k] = pack2(ev[2 * k], ev[2 * k + 1]);
        #pragma unroll
        for (int k = 0; k < 4; ++k) u1[k] = pack2(ev[8 + 2 * k], ev[9 + 2 * k]);
        *(uint4v*)&nbvp[n * 68 + c16 * 8]     = u0;
        *(uint4v*)&nbvp[n * 68 + c16 * 8 + 4] = u1;
        float acc[8];
        #pragma unroll
        for (int h = 0; h < 8; ++h) {
            const float4v* qrow = (const float4v*)&qk[h * 132 + j0];
            float s = 0.f;
            #pragma unroll
            for (int c = 0; c < 4; ++c) {
                float4v q = qrow[c];
                #pragma unroll
                for (int k = 0; k < 4; ++k) s += q[k] * kv[c * 4 + k];
            }
            acc[h] = s;
        }
        #pragma unroll
        for (int off = 1; off < 8; off <<= 1) {
            #pragma unroll
            for (int h = 0; h < 8; ++h) acc[h] += __shfl_xor(acc[h], off, 8);
        }
        if (c16 == 0) {
            #pragma unroll
            for (int h = 0; h < 8; ++h) {
                float lf = (acc[h] + qb[h]) * ATTN_SCALE;
                if (!mmask[n]) lf = -1e30f;
                Lg[h][n] = lf;
            }
        }
    }
    __syncthreads();

    {
        int h = t >> 5, n = t & 31;
        float lf = Lg[h][n];
        float mx = lf;
        #pragma unroll
        for (int off = 16; off >= 1; off >>= 1) mx = fmaxf(mx, __shfl_xor(mx, off, 32));
        float p = __expf(lf - mx);
        float s = p;
        #pragma unroll
        for (int off = 16; off >= 1; off >>= 1) s += __shfl_xor(s, off, 32);
        Lg[h][n] = p / s;
    }
    __syncthreads();

    {
        int h = t >> 5, c4 = t & 31;
        float4v a = (float4v){0.f, 0.f, 0.f, 0.f};
        #pragma unroll 8
        for (int n = 0; n < 32; ++n) {
            float p = Lg[h][n];
            unsigned int w0 = nbvp[n * 68 + c4 * 2];
            unsigned int w1 = nbvp[n * 68 + c4 * 2 + 1];
            a[0] += p * unpk_lo(w0);
            a[1] += p * unpk_hi(w0);
            a[2] += p * unpk_lo(w1);
            a[3] += p * unpk_hi(w1);
        }
        *(float4v*)&pv[h * 132 + c4 * 4] = a;
    }
    __syncthreads();

    {
        int half = t >> 7, d = t & 127, j0 = half * 64;
        int h = d >> 4;
        const float4v* p4 = (const float4v*)&pv[h * 132 + j0];
        float acc = 0.f;
        #pragma unroll 4
        for (int c = 0; c < 16; ++c) {
            float4v p = p4[c];
            #pragma unroll
            for (int k = 0; k < 4; ++k)
                acc += p[k] * Wv[(j0 + c * 4 + k) * 128 + d];
        }
        ypart[half][d] = acc;
    }
    __syncthreads();
    if (t < 128) oat[t] = ypart[0][t] + ypart[1][t] + bv[t];
    __syncthreads();

    {
        int half = t >> 7, d = t & 127, j0 = half * 64;
        const float4v* o4 = (const float4v*)&oat[j0];
        float acc = 0.f;
        #pragma unroll 4
        for (int c = 0; c < 16; ++c) {
            float4v o = o4[c];
            #pragma unroll
            for (int k = 0; k < 4; ++k)
                acc += o[k] * Wo[(j0 + c * 4 + k) * 128 + d];
        }
        ypart[half][d] = acc;
    }
    __syncthreads();

    float x = 0.f;
    if (t < 128) {
        x = er[t] + ypart[0][t] + ypart[1][t] + bo[t];
        float s1 = x, s2 = x * x;
        #pragma unroll
        for (int off = 32; off >= 1; off >>= 1) {
            s1 += __shfl_xor(s1, off, 64);
            s2 += __shfl_xor(s2, off, 64);
        }
        if ((t & 63) == 0) { red[(t >> 6) * 2] = s1; red[(t >> 6) * 2 + 1] = s2; }
    }
    __syncthreads();
    if (t < 128) {
        float mu  = (red[0] + red[2]) * (1.0f / 128.0f);
        float ms  = (red[1] + red[3]) * (1.0f / 128.0f);
        float var = fmaxf(ms - mu * mu, 0.0f);
        float rs  = rsqrtf(var + LN_EPS);
        outp[m * 128 + t] = (x - mu) * rs * gamma_[t] + beta_[t];
    }
}

// ---------------------------------------------------------------------------
extern "C" void kernel_launch(void* const* d_in, const int* in_sizes, int n_in,
                              void* d_out, int out_size, void* d_ws, size_t ws_size,
                              hipStream_t stream) {
    const float* entity    = (const float*)d_in[0];
    const int*   nidx      = (const int*)d_in[1];
    const int*   nrel      = (const int*)d_in[2];
    const int*   nmask     = (const int*)d_in[3];
    const float* Wq        = (const float*)d_in[4];
    const float* bq        = (const float*)d_in[5];
    const float* Wk        = (const float*)d_in[6];
    const float* bk        = (const float*)d_in[7];
    const float* Wv        = (const float*)d_in[8];
    const float* bv        = (const float*)d_in[9];
    const float* Wo        = (const float*)d_in[10];
    const float* bo        = (const float*)d_in[11];
    const float* rel_table = (const float*)d_in[12];
    const float* gamma_    = (const float*)d_in[13];
    const float* beta_     = (const float*)d_in[14];

    // workspace layout (fp32): EQ 8M | EK 8M | EV 8M | OAT 8M | RK 121344
    char* ws = (char*)d_ws;
    float* EQ  = (float*)(ws + 0);
    float* EK  = (float*)(ws + 8388608);
    float* EV  = (float*)(ws + 16777216);
    float* OAT = (float*)(ws + 25165824);
    float* RK  = (float*)(ws + 33554432);
    const size_t NEED = 33554432 + 121344;

    if (ws_size >= NEED) {
        gemm4<<<dim3(128, 4), 256, 0, stream>>>(
            entity, rel_table, Wq, bq, Wk, bk, Wv, bv, EQ, EK, EV, RK);
        attn_gather<<<dim3(M_NODES / 4), 256, 0, stream>>>(
            nidx, nrel, nmask, EQ, EK, EV, RK, OAT);
        gemm_wo_ln<<<dim3(128), 256, 0, stream>>>(
            OAT, Wo, bo, entity, gamma_, beta_, (float*)d_out);
    } else {
        rga_fused<<<dim3(M_NODES), 256, 0, stream>>>(
            entity, nidx, nrel, nmask, Wq, bq, Wk, bk, Wv, bv, Wo, bo,
            rel_table, gamma_, beta_, (float*)d_out);
    }
}

// Round 7
// 160.472 us; speedup vs baseline: 2.5037x; 1.3553x over previous
//
#include <hip/hip_runtime.h>

#define M_NODES 16384
#define NNBR 32
#define RREL 237
#define ATTN_SCALE 0.25f   // (128/8)^-0.5
#define LN_EPS 1e-5f

typedef float float4v __attribute__((ext_vector_type(4)));
typedef float float2v __attribute__((ext_vector_type(2)));
typedef unsigned int uint4v __attribute__((ext_vector_type(4)));
typedef short short8 __attribute__((ext_vector_type(8)));
typedef float floatx4 __attribute__((ext_vector_type(4)));

__device__ __forceinline__ float bfu2f(unsigned short u) {
    return __builtin_bit_cast(float, ((unsigned int)u) << 16);
}
__device__ __forceinline__ unsigned short f2bfu(float f) {
    unsigned int x = __builtin_bit_cast(unsigned int, f);
    unsigned int lsb = (x >> 16) & 1u;
    x += 0x7fffu + lsb;                 // round-to-nearest-even
    return (unsigned short)(x >> 16);
}
__device__ __forceinline__ unsigned int pack2(float a, float b) {
    return (unsigned int)f2bfu(a) | ((unsigned int)f2bfu(b) << 16);
}
__device__ __forceinline__ float unpk_lo(unsigned int u) {
    return __builtin_bit_cast(float, u << 16);
}
__device__ __forceinline__ float unpk_hi(unsigned int u) {
    return __builtin_bit_cast(float, u & 0xffff0000u);
}

// ===========================================================================
// FAST PATH
// ===========================================================================

// T: transpose + convert Wq,Wk,Wv,Wo (fp32 row-major) -> WT (bf16, WT[c][r]).
// grid = 32: mat = bx>>3, slab = bx&7 (16 rows each)
__global__ __launch_bounds__(256) void transpose_w4(
    const float* __restrict__ Wq, const float* __restrict__ Wk,
    const float* __restrict__ Wv, const float* __restrict__ Wo,
    unsigned short* __restrict__ WqT, unsigned short* __restrict__ WkT,
    unsigned short* __restrict__ WvT, unsigned short* __restrict__ WoT) {
    int mat  = blockIdx.x >> 3;
    int slab = blockIdx.x & 7;
    const float* W = (mat == 0) ? Wq : (mat == 1) ? Wk : (mat == 2) ? Wv : Wo;
    unsigned short* WT = (mat == 0) ? WqT : (mat == 1) ? WkT : (mat == 2) ? WvT : WoT;
    int t = threadIdx.x;
    #pragma unroll
    for (int i = 0; i < 8; ++i) {
        int idx = t + 256 * i;            // 0..2047 within slab
        int r = slab * 16 + (idx >> 7);
        int c = idx & 127;
        WT[c * 128 + r] = f2bfu(W[r * 128 + c]);
    }
}

// MFMA GEMM core: one 256-thr block computes OUT[rbase..+127][0..127] =
// A_f32[rows][128] @ W (W given transposed-bf16 WT[col][k]).
// Wave w: rows rbase+w*32 .. +31. Returns acc[2][8] per lane.
__device__ __forceinline__ void mfma_core(
    const float* __restrict__ A, const unsigned short* __restrict__ WT,
    int arows, int rbase, unsigned short* lw, floatx4 acc[2][8]) {
    int t = threadIdx.x;
    // stage WT into LDS, stride 136 bf16
    #pragma unroll
    for (int i = 0; i < 8; ++i) {
        int ci = t + 256 * i;          // 2048 chunks of 8 bf16
        int r  = ci >> 4;
        int c8 = ci & 15;
        *(short8*)&lw[r * 136 + c8 * 8] = *(const short8*)&WT[r * 128 + c8 * 8];
    }
    __syncthreads();

    int wave = t >> 6, lane = t & 63;
    int lm = lane & 15, quad = lane >> 4;
    int m0 = rbase + wave * 32;

    #pragma unroll
    for (int i = 0; i < 2; ++i)
        #pragma unroll
        for (int c = 0; c < 8; ++c) acc[i][c] = (floatx4){0.f, 0.f, 0.f, 0.f};

    int r0 = m0 + lm;      if (r0 >= arows) r0 = arows - 1;
    int r1 = m0 + 16 + lm; if (r1 >= arows) r1 = arows - 1;

    #pragma unroll
    for (int ks = 0; ks < 4; ++ks) {
        int koff = ks * 32 + quad * 8;
        float4v f00 = *(const float4v*)&A[r0 * 128 + koff];
        float4v f01 = *(const float4v*)&A[r0 * 128 + koff + 4];
        float4v f10 = *(const float4v*)&A[r1 * 128 + koff];
        float4v f11 = *(const float4v*)&A[r1 * 128 + koff + 4];
        short8 a0, a1;
        #pragma unroll
        for (int j = 0; j < 4; ++j) {
            a0[j]     = (short)f2bfu(f00[j]);
            a0[4 + j] = (short)f2bfu(f01[j]);
            a1[j]     = (short)f2bfu(f10[j]);
            a1[4 + j] = (short)f2bfu(f11[j]);
        }
        #pragma unroll
        for (int c = 0; c < 8; ++c) {
            short8 b = *(const short8*)&lw[(c * 16 + lm) * 136 + koff];
            acc[0][c] = __builtin_amdgcn_mfma_f32_16x16x32_bf16(a0, b, acc[0][c], 0, 0, 0);
            acc[1][c] = __builtin_amdgcn_mfma_f32_16x16x32_bf16(a1, b, acc[1][c], 0, 0, 0);
        }
    }
}

// G1: four projections. grid (128, 4):
//   y=0: EQ (fp32)     = entity@Wq + bq
//   y=1: EKV K-half    = entity@Wk          (bias folded into RK)
//   y=2: EKV V-half    = entity@Wv + bv
//   y=3: RKb (bf16)    = rel_table@Wk + bk  (237 rows)
__global__ __launch_bounds__(256) void gemm4_mfma(
    const float* __restrict__ entity, const float* __restrict__ rel_table,
    const unsigned short* __restrict__ WqT, const unsigned short* __restrict__ WkT,
    const unsigned short* __restrict__ WvT,
    const float* __restrict__ bq, const float* __restrict__ bk,
    const float* __restrict__ bv,
    float* __restrict__ EQ, unsigned short* __restrict__ EKV,
    unsigned short* __restrict__ RKb) {
    __shared__ __align__(16) unsigned short lw[128 * 136];

    int y = blockIdx.y;
    const float* A; const unsigned short* WT; const float* bias; int arows;
    unsigned short* outb; int ostride, ooff; int f32out;
    if (y == 0)      { A = entity;    WT = WqT; bias = bq;      arows = M_NODES; outb = nullptr; ostride = 128; ooff = 0;   f32out = 1; }
    else if (y == 1) { A = entity;    WT = WkT; bias = nullptr; arows = M_NODES; outb = EKV;     ostride = 256; ooff = 0;   f32out = 0; }
    else if (y == 2) { A = entity;    WT = WvT; bias = bv;      arows = M_NODES; outb = EKV;     ostride = 256; ooff = 128; f32out = 0; }
    else             { A = rel_table; WT = WkT; bias = bk;      arows = RREL;    outb = RKb;     ostride = 128; ooff = 0;   f32out = 0; }

    int rbase = blockIdx.x * 128;
    if (rbase >= arows) return;

    floatx4 acc[2][8];
    mfma_core(A, WT, arows, rbase, lw, acc);

    int t = threadIdx.x, wave = t >> 6, lane = t & 63;
    int lm = lane & 15, quad = lane >> 4;
    int m0 = rbase + wave * 32;

    #pragma unroll
    for (int c = 0; c < 8; ++c) {
        int col = c * 16 + lm;
        float bb = bias ? bias[col] : 0.0f;
        #pragma unroll
        for (int i = 0; i < 2; ++i) {
            int rb = m0 + i * 16 + quad * 4;
            #pragma unroll
            for (int j = 0; j < 4; ++j) {
                int r = rb + j;
                if (r < arows) {
                    float v = acc[i][c][j] + bb;
                    if (f32out) EQ[r * 128 + col] = v;
                    else        outb[r * ostride + ooff + col] = f2bfu(v);
                }
            }
        }
    }
}

// A: wave-per-node attention over bf16 tables. grid 4096 x 256 (4 nodes/block).
__global__ __launch_bounds__(256) void attn_gather(
    const int* __restrict__ nidx, const int* __restrict__ nrel,
    const int* __restrict__ nmask,
    const float* __restrict__ EQ, const unsigned short* __restrict__ EKV,
    const unsigned short* __restrict__ RKb,
    float* __restrict__ OAT) {
    __shared__ float Pl[4][8][32];
    __shared__ int mix[4][32];

    int w = threadIdx.x >> 6, l = threadIdx.x & 63;
    int m = blockIdx.x * 4 + w;
    int half = l >> 5, n = l & 31;

    int mk = nmask[m * NNBR + n];
    int ix = nidx[m * NNBR + n];
    int ir = nrel[m * NNBR + n];
    if (!mk) { ix = 0; ir = 0; }
    ix = ix < 0 ? 0 : (ix > M_NODES - 1 ? M_NODES - 1 : ix);
    ir = ir < 0 ? 0 : (ir > RREL - 1 ? RREL - 1 : ir);
    if (l < 32) mix[w][l] = ix;

    // logits for heads half*4..half*4+3 (dims half*64..half*64+63)
    const float4v* eq4 = (const float4v*)&EQ[m * 128 + half * 64];
    const unsigned short* kp = &EKV[ix * 256 + half * 64];
    const unsigned short* rp = &RKb[ir * 128 + half * 64];
    float acc[4] = {0.f, 0.f, 0.f, 0.f};
    #pragma unroll
    for (int c2 = 0; c2 < 8; ++c2) {
        float4v q0 = eq4[2 * c2], q1 = eq4[2 * c2 + 1];
        short8 k8 = *(const short8*)&kp[c2 * 8];
        short8 r8 = *(const short8*)&rp[c2 * 8];
        int hh = c2 >> 1;
        #pragma unroll
        for (int j = 0; j < 4; ++j) {
            acc[hh] += q0[j] * (bfu2f((unsigned short)k8[j]) + bfu2f((unsigned short)r8[j]));
            acc[hh] += q1[j] * (bfu2f((unsigned short)k8[4 + j]) + bfu2f((unsigned short)r8[4 + j]));
        }
    }
    #pragma unroll
    for (int hh = 0; hh < 4; ++hh) {
        float lf = acc[hh] * ATTN_SCALE;
        if (!mk) lf = -1e30f;
        float mx = lf;
        #pragma unroll
        for (int off = 16; off >= 1; off >>= 1) mx = fmaxf(mx, __shfl_xor(mx, off, 32));
        float p = __expf(lf - mx);
        float s = p;
        #pragma unroll
        for (int off = 16; off >= 1; off >>= 1) s += __shfl_xor(s, off, 32);
        Pl[w][half * 4 + hh][n] = p / s;
    }
    // PV: lane -> dims 2l, 2l+1 (head h0 = l>>3); V half of EKV row
    int h0 = l >> 3;
    float o0 = 0.f, o1 = 0.f;
    #pragma unroll 8
    for (int n2 = 0; n2 < 32; ++n2) {
        float pp = Pl[w][h0][n2];
        int ixx = mix[w][n2];
        unsigned int u = *(const unsigned int*)&EKV[ixx * 256 + 128 + 2 * l];
        o0 += pp * unpk_lo(u);
        o1 += pp * unpk_hi(u);
    }
    float2v o; o[0] = o0; o[1] = o1;
    *(float2v*)&OAT[m * 128 + 2 * l] = o;
}

// G2: Y = OAT@Wo + bo + entity -> LayerNorm -> OUT. grid 256, 128 thr (2 waves,
// 64 rows/block). LN row-stats via width-16 shuffles in the MFMA C layout.
__global__ __launch_bounds__(128) void gemm_wo_ln(
    const float* __restrict__ OAT, const unsigned short* __restrict__ WoT,
    const float* __restrict__ bo, const float* __restrict__ entity,
    const float* __restrict__ gamma_, const float* __restrict__ beta_,
    float* __restrict__ OUT) {
    __shared__ __align__(16) unsigned short lw[128 * 136];

    int t = threadIdx.x;
    // stage WoT (128 threads, 16 iters)
    #pragma unroll
    for (int i = 0; i < 16; ++i) {
        int ci = t + 128 * i;
        int r  = ci >> 4;
        int c8 = ci & 15;
        *(short8*)&lw[r * 136 + c8 * 8] = *(const short8*)&WoT[r * 128 + c8 * 8];
    }
    __syncthreads();

    int wave = t >> 6, lane = t & 63;
    int lm = lane & 15, quad = lane >> 4;
    int rbase = blockIdx.x * 64;
    int m0 = rbase + wave * 32;

    floatx4 acc[2][8];
    #pragma unroll
    for (int i = 0; i < 2; ++i)
        #pragma unroll
        for (int c = 0; c < 8; ++c) acc[i][c] = (floatx4){0.f, 0.f, 0.f, 0.f};

    int r0 = m0 + lm, r1 = m0 + 16 + lm;
    #pragma unroll
    for (int ks = 0; ks < 4; ++ks) {
        int koff = ks * 32 + quad * 8;
        float4v f00 = *(const float4v*)&OAT[r0 * 128 + koff];
        float4v f01 = *(const float4v*)&OAT[r0 * 128 + koff + 4];
        float4v f10 = *(const float4v*)&OAT[r1 * 128 + koff];
        float4v f11 = *(const float4v*)&OAT[r1 * 128 + koff + 4];
        short8 a0, a1;
        #pragma unroll
        for (int j = 0; j < 4; ++j) {
            a0[j]     = (short)f2bfu(f00[j]);
            a0[4 + j] = (short)f2bfu(f01[j]);
            a1[j]     = (short)f2bfu(f10[j]);
            a1[4 + j] = (short)f2bfu(f11[j]);
        }
        #pragma unroll
        for (int c = 0; c < 8; ++c) {
            short8 b = *(const short8*)&lw[(c * 16 + lm) * 136 + koff];
            acc[0][c] = __builtin_amdgcn_mfma_f32_16x16x32_bf16(a0, b, acc[0][c], 0, 0, 0);
            acc[1][c] = __builtin_amdgcn_mfma_f32_16x16x32_bf16(a1, b, acc[1][c], 0, 0, 0);
        }
    }

    // per-lane column constants
    float bb[8], gg[8], be[8];
    #pragma unroll
    for (int c = 0; c < 8; ++c) {
        int col = c * 16 + lm;
        bb[c] = bo[col]; gg[c] = gamma_[col]; be[c] = beta_[col];
    }
    // epilogue: residual + LN per row (rows m0+i*16+quad*4+j)
    #pragma unroll
    for (int i = 0; i < 2; ++i) {
        #pragma unroll
        for (int j = 0; j < 4; ++j) {
            int r = m0 + i * 16 + quad * 4 + j;
            float y[8];
            float s1 = 0.f, s2 = 0.f;
            #pragma unroll
            for (int c = 0; c < 8; ++c) {
                float v = acc[i][c][j] + bb[c] + entity[r * 128 + c * 16 + lm];
                y[c] = v; s1 += v; s2 += v * v;
            }
            #pragma unroll
            for (int off = 8; off >= 1; off >>= 1) {
                s1 += __shfl_xor(s1, off, 16);
                s2 += __shfl_xor(s2, off, 16);
            }
            float mu  = s1 * (1.0f / 128.0f);
            float var = fmaxf(s2 * (1.0f / 128.0f) - mu * mu, 0.0f);
            float rs  = rsqrtf(var + LN_EPS);
            #pragma unroll
            for (int c = 0; c < 8; ++c)
                OUT[r * 128 + c * 16 + lm] = (y[c] - mu) * rs * gg[c] + be[c];
        }
    }
}

// ===========================================================================
// FALLBACK (round-5 fused kernel, passes at ~314 µs) — used if ws too small
// ===========================================================================
__global__ __launch_bounds__(256, 6) void rga_fused(
    const float* __restrict__ entity,
    const int* __restrict__ nidx,
    const int* __restrict__ nrel,
    const int* __restrict__ nmask,
    const float* __restrict__ Wq, const float* __restrict__ bq,
    const float* __restrict__ Wk, const float* __restrict__ bk,
    const float* __restrict__ Wv, const float* __restrict__ bv,
    const float* __restrict__ Wo, const float* __restrict__ bo,
    const float* __restrict__ rel_table,
    const float* __restrict__ gamma_, const float* __restrict__ beta_,
    float* __restrict__ outp) {
    __shared__ __align__(16) float er[128];
    __shared__ __align__(16) float qv[128];
    __shared__ float qb[8];
    __shared__ __align__(16) float qk[8 * 132];
    __shared__ __align__(16) unsigned int nbvp[32 * 68];
    __shared__ float Lg[8][33];
    __shared__ __align__(16) float pv[8 * 132];
    __shared__ __align__(16) float oat[128];
    __shared__ float ypart[2][128];
    __shared__ float red[4];
    __shared__ int midx[32], mrel[32], mmask[32];

    int m = blockIdx.x;
    int t = threadIdx.x;

    if (t < 32) {
        int mk = nmask[m * NNBR + t];
        int ix = nidx[m * NNBR + t];
        int ir = nrel[m * NNBR + t];
        if (!mk) { ix = 0; ir = 0; }
        ix = ix < 0 ? 0 : (ix > M_NODES - 1 ? M_NODES - 1 : ix);
        ir = ir < 0 ? 0 : (ir > RREL - 1 ? RREL - 1 : ir);
        mmask[t] = mk; midx[t] = ix; mrel[t] = ir;
    }
    if (t >= 128) er[t - 128] = entity[m * 128 + (t - 128)];
    __syncthreads();

    {
        int half = t >> 7, d = t & 127, j0 = half * 64;
        const float4v* e4 = (const float4v*)&er[j0];
        float acc = 0.f;
        #pragma unroll 4
        for (int c = 0; c < 16; ++c) {
            float4v ev = e4[c];
            #pragma unroll
            for (int k = 0; k < 4; ++k)
                acc += ev[k] * Wq[(j0 + c * 4 + k) * 128 + d];
        }
        ypart[half][d] = acc;
    }
    __syncthreads();
    if (t < 128) qv[t] = ypart[0][t] + ypart[1][t] + bq[t];
    __syncthreads();

    #pragma unroll
    for (int rep = 0; rep < 4; ++rep) {
        int o = rep * 256 + t;
        int h = o >> 7, j = o & 127;
        const float4v* wr = (const float4v*)&Wk[j * 128 + h * 16];
        const float4v* q4 = (const float4v*)&qv[h * 16];
        float s = 0.f;
        #pragma unroll
        for (int c = 0; c < 4; ++c) {
            float4v w = wr[c], q = q4[c];
            #pragma unroll
            for (int k = 0; k < 4; ++k) s += w[k] * q[k];
        }
        qk[h * 132 + j] = s;
    }
    if (t < 8) {
        float s = 0.f;
        #pragma unroll
        for (int dh = 0; dh < 16; ++dh) s += qv[t * 16 + dh] * bk[t * 16 + dh];
        qb[t] = s;
    }
    __syncthreads();

    {
        int n = t >> 3, c16 = t & 7, j0 = c16 * 16;
        int ix = midx[n], ir = mrel[n];
        const float4v* ep = (const float4v*)&entity[ix * 128 + j0];
        const float4v* rp = (const float4v*)&rel_table[ir * 128 + j0];
        float ev[16], kv[16];
        #pragma unroll
        for (int c = 0; c < 4; ++c) {
            float4v e4 = ep[c], r4 = rp[c];
            #pragma unroll
            for (int k = 0; k < 4; ++k) {
                ev[c * 4 + k] = e4[k];
                kv[c * 4 + k] = e4[k] + r4[k];
            }
        }
        uint4v u0, u1;
        #pragma unroll
        for (int k = 0; k < 4; ++k) u0[k] = pack2(ev[2 * k], ev[2 * k + 1]);
        #pragma unroll
        for (int k = 0; k < 4; ++k) u1[k] = pack2(ev[8 + 2 * k], ev[9 + 2 * k]);
        *(uint4v*)&nbvp[n * 68 + c16 * 8]     = u0;
        *(uint4v*)&nbvp[n * 68 + c16 * 8 + 4] = u1;
        float acc[8];
        #pragma unroll
        for (int h = 0; h < 8; ++h) {
            const float4v* qrow = (const float4v*)&qk[h * 132 + j0];
            float s = 0.f;
            #pragma unroll
            for (int c = 0; c < 4; ++c) {
                float4v q = qrow[c];
                #pragma unroll
                for (int k = 0; k < 4; ++k) s += q[k] * kv[c * 4 + k];
            }
            acc[h] = s;
        }
        #pragma unroll
        for (int off = 1; off < 8; off <<= 1) {
            #pragma unroll
            for (int h = 0; h < 8; ++h) acc[h] += __shfl_xor(acc[h], off, 8);
        }
        if (c16 == 0) {
            #pragma unroll
            for (int h = 0; h < 8; ++h) {
                float lf = (acc[h] + qb[h]) * ATTN_SCALE;
                if (!mmask[n]) lf = -1e30f;
                Lg[h][n] = lf;
            }
        }
    }
    __syncthreads();

    {
        int h = t >> 5, n = t & 31;
        float lf = Lg[h][n];
        float mx = lf;
        #pragma unroll
        for (int off = 16; off >= 1; off >>= 1) mx = fmaxf(mx, __shfl_xor(mx, off, 32));
        float p = __expf(lf - mx);
        float s = p;
        #pragma unroll
        for (int off = 16; off >= 1; off >>= 1) s += __shfl_xor(s, off, 32);
        Lg[h][n] = p / s;
    }
    __syncthreads();

    {
        int h = t >> 5, c4 = t & 31;
        float4v a = (float4v){0.f, 0.f, 0.f, 0.f};
        #pragma unroll 8
        for (int n = 0; n < 32; ++n) {
            float p = Lg[h][n];
            unsigned int w0 = nbvp[n * 68 + c4 * 2];
            unsigned int w1 = nbvp[n * 68 + c4 * 2 + 1];
            a[0] += p * unpk_lo(w0);
            a[1] += p * unpk_hi(w0);
            a[2] += p * unpk_lo(w1);
            a[3] += p * unpk_hi(w1);
        }
        *(float4v*)&pv[h * 132 + c4 * 4] = a;
    }
    __syncthreads();

    {
        int half = t >> 7, d = t & 127, j0 = half * 64;
        int h = d >> 4;
        const float4v* p4 = (const float4v*)&pv[h * 132 + j0];
        float acc = 0.f;
        #pragma unroll 4
        for (int c = 0; c < 16; ++c) {
            float4v p = p4[c];
            #pragma unroll
            for (int k = 0; k < 4; ++k)
                acc += p[k] * Wv[(j0 + c * 4 + k) * 128 + d];
        }
        ypart[half][d] = acc;
    }
    __syncthreads();
    if (t < 128) oat[t] = ypart[0][t] + ypart[1][t] + bv[t];
    __syncthreads();

    {
        int half = t >> 7, d = t & 127, j0 = half * 64;
        const float4v* o4 = (const float4v*)&oat[j0];
        float acc = 0.f;
        #pragma unroll 4
        for (int c = 0; c < 16; ++c) {
            float4v o = o4[c];
            #pragma unroll
            for (int k = 0; k < 4; ++k)
                acc += o[k] * Wo[(j0 + c * 4 + k) * 128 + d];
        }
        ypart[half][d] = acc;
    }
    __syncthreads();

    float x = 0.f;
    if (t < 128) {
        x = er[t] + ypart[0][t] + ypart[1][t] + bo[t];
        float s1 = x, s2 = x * x;
        #pragma unroll
        for (int off = 32; off >= 1; off >>= 1) {
            s1 += __shfl_xor(s1, off, 64);
            s2 += __shfl_xor(s2, off, 64);
        }
        if ((t & 63) == 0) { red[(t >> 6) * 2] = s1; red[(t >> 6) * 2 + 1] = s2; }
    }
    __syncthreads();
    if (t < 128) {
        float mu  = (red[0] + red[2]) * (1.0f / 128.0f);
        float ms  = (red[1] + red[3]) * (1.0f / 128.0f);
        float var = fmaxf(ms - mu * mu, 0.0f);
        float rs  = rsqrtf(var + LN_EPS);
        outp[m * 128 + t] = (x - mu) * rs * gamma_[t] + beta_[t];
    }
}

// ---------------------------------------------------------------------------
extern "C" void kernel_launch(void* const* d_in, const int* in_sizes, int n_in,
                              void* d_out, int out_size, void* d_ws, size_t ws_size,
                              hipStream_t stream) {
    const float* entity    = (const float*)d_in[0];
    const int*   nidx      = (const int*)d_in[1];
    const int*   nrel      = (const int*)d_in[2];
    const int*   nmask     = (const int*)d_in[3];
    const float* Wq        = (const float*)d_in[4];
    const float* bq        = (const float*)d_in[5];
    const float* Wk        = (const float*)d_in[6];
    const float* bk        = (const float*)d_in[7];
    const float* Wv        = (const float*)d_in[8];
    const float* bv        = (const float*)d_in[9];
    const float* Wo        = (const float*)d_in[10];
    const float* bo        = (const float*)d_in[11];
    const float* rel_table = (const float*)d_in[12];
    const float* gamma_    = (const float*)d_in[13];
    const float* beta_     = (const float*)d_in[14];

    // ws layout: EKV(bf16) 8M @0 | OAT(f32) 8M @8M | EQ(f32) 8M @16M |
    //            RKb(bf16) 60672 @25165824 | WqT/WkT/WvT/WoT bf16 32KB each
    char* ws = (char*)d_ws;
    unsigned short* EKV = (unsigned short*)(ws + 0);
    float*          OAT = (float*)(ws + 8388608);
    float*          EQ  = (float*)(ws + 16777216);
    unsigned short* RKb = (unsigned short*)(ws + 25165824);
    unsigned short* WqT = (unsigned short*)(ws + 25226496);
    unsigned short* WkT = (unsigned short*)(ws + 25259264);
    unsigned short* WvT = (unsigned short*)(ws + 25292032);
    unsigned short* WoT = (unsigned short*)(ws + 25324800);
    const size_t NEED = 25357568;

    if (ws_size >= NEED) {
        transpose_w4<<<dim3(32), 256, 0, stream>>>(Wq, Wk, Wv, Wo, WqT, WkT, WvT, WoT);
        gemm4_mfma<<<dim3(128, 4), 256, 0, stream>>>(
            entity, rel_table, WqT, WkT, WvT, bq, bk, bv, EQ, EKV, RKb);
        attn_gather<<<dim3(M_NODES / 4), 256, 0, stream>>>(
            nidx, nrel, nmask, EQ, EKV, RKb, OAT);
        gemm_wo_ln<<<dim3(256), 128, 0, stream>>>(
            OAT, WoT, bo, entity, gamma_, beta_, (float*)d_out);
    } else {
        rga_fused<<<dim3(M_NODES), 256, 0, stream>>>(
            entity, nidx, nrel, nmask, Wq, bq, Wk, bk, Wv, bv, Wo, bo,
            rel_table, gamma_, beta_, (float*)d_out);
    }
}